// Round 1
// baseline (167.983 us; speedup 1.0000x reference)
//
#include <hip/hip_runtime.h>
#include <hip/hip_bf16.h>

// 2D-MDLSTM (4 directions) + FC head for MI355X — round 16.
//
// R15 analysis: per-step 3617 cyc decomposes as LDS ~1360 + MFMA ~1090
// (= MfmaUtil 25%) + VALU/trans ~1050 (= VALUBusy 53%) + barrier — the 55
// lockstep barriers serialize the pipes, so wall ~= SUM of pipe work.
// R16 reduces the sum with t-invariant addressing:
//   1. Absolute-row task mapping: lane->row fixed for the whole kernel, all
//      LDS offsets hoisted out of the t-loop (slots were already absolute:
//      slot = 27-row). Inactive rows masked on store ((unsigned)(t-r)<=27);
//      per-wave tile-activity tests skip wholly-inactive tiles; both-active
//      tiles run as one interleaved dual-task body (10 indep MFMA chains).
//   2. 5th MFMA K-step dropped: bias -> MFMA C-init (free), x*Wx -> 4 f32
//      FMAs/gate in C-init with x loaded straight from global (L1-resident,
//      vmcnt pipe, off the LDS pipe). MFMA/task 25->20; a-reads 5->4 b128;
//      per-step tail-wave x staging (barrier skew) removed.
//   3. c_left kept in a per-lane register (same lane writes and reads it);
//      only c_up goes through LDS. c-loads/task 8->4.
// Structure kept from R12: 256 WGs (4 dir x 64 batch-pairs) x 512 thr;
// register-resident gate-scaled U fragments (exp2-folded, compiler puts
// them in AGPRs); double-buffered LDS frontier (S_H=104/S_C=68, slot 28 =
// permanent zero row); merged transcendentals with cn<=22 clamp; t-loop x2
// unrolled so buffer indices const-fold; dummy rows (>=28) clamp to row 27
// and duplicate same-wave same-value writes.

#define GRIDN 28
#define BATCH 128
#define HID   64
#define NDIR  4
#define FC_HD 512
#define OUT_N 10
#define BT    2
#define NTHR  512
#define NSLOT 29          // 28 frontier rows + permanent-zero row (slot 28)
#define S_H   104         // f16/slot: [0,64) h | rest pad (bank stagger)
#define S_C   68          // float/slot: 64 c + 4 pad

typedef _Float16 f16;
typedef _Float16 f16x8 __attribute__((ext_vector_type(8)));
typedef float    f32x4 __attribute__((ext_vector_type(4)));

#define LOG2E  1.44269504088896340736f
#define LOG2E2 2.88539008177792681472f

__device__ __forceinline__ float rcpf(float x) { return __builtin_amdgcn_rcpf(x); }
__device__ __forceinline__ float ex2(float x)  { return __builtin_amdgcn_exp2f(x); }

__global__ __launch_bounds__(NTHR)
void mdlstm_kernel(const float* __restrict__ x,    // [B][28][28]
                   const float* __restrict__ Wx,   // [4][320]
                   const float* __restrict__ U,    // [4][128][320]
                   const float* __restrict__ bias, // [4][320]
                   float* __restrict__ Hout)       // [4][B][64]
{
    const int d    = blockIdx.x & 3;
    const int tile = blockIdx.x >> 2;     // 0..63 batch-pair
    const int tid  = threadIdx.x;
    const int lane = tid & 63;
    const int wave = tid >> 6;            // 0..7
    const int wm   = wave >> 2;           // tile-group 0/1 -> tiles {wm, wm+2}
    const int wh   = wave & 3;            // h-subtile (n = wh*16 + l16)
    const int l16  = lane & 15;
    const int q    = lane >> 4;
    const int nb   = wh * 16 + l16;       // this lane's h index 0..63

    __shared__ __align__(16) f16 Fh[2][BT][NSLOT * S_H];
    __shared__ float             Fc[2][BT][NSLOT * S_C];

    for (int i = tid; i < 2 * BT * NSLOT * S_H; i += NTHR) ((f16*)Fh)[i] = (f16)0.0f;
    for (int i = tid; i < 2 * BT * NSLOT * S_C; i += NTHR) ((float*)Fc)[i] = 0.0f;

    // ---- B-fragments in registers, gate-scaled (K-steps 0..3 only):
    // sigmoid gates scaled by -log2e (sig = rcp(1+2^acc)); g gate by +2log2e.
    // x*Wx and bias are folded into the MFMA C-initializer instead of a 5th
    // K-step: sWx/sB preloaded per lane-column.
    f16x8 bf[5][4];
    float sWx[5], sB[5];
#pragma unroll
    for (int g = 0; g < 5; ++g) {
        const float sc = (g == 4) ? LOG2E2 : -LOG2E;
        int n = g * 64 + nb;
#pragma unroll
        for (int ks = 0; ks < 4; ++ks) {
            f16x8 v;
            int kb = ks * 32 + q * 8;
#pragma unroll
            for (int j = 0; j < 8; ++j)
                v[j] = (f16)(sc * U[(d * 128 + kb + j) * 320 + n]);
            bf[g][ks] = v;
        }
        sWx[g] = sc * Wx[d * 320 + n];
        sB[g]  = sc * bias[d * 320 + n];
    }

    // ---- t-invariant addresses (absolute-row mapping; hoisted for the
    // whole kernel). Task u covers M-rows (wm+2u)*16 .. +15; row = mrow>>1
    // clamped to 27 (dummy rows duplicate row 27), batch = mrow&1.
    int aoffs[2];                          // A-fragment base (f16 index)
#pragma unroll
    for (int u = 0; u < 2; ++u) {
        int mA = (wm + 2 * u) * 16 + l16;
        int rA = mA >> 1; if (rA > GRIDN - 1) rA = GRIDN - 1;
        int bA = mA & 1;
        aoffs[u] = (bA * NSLOT + (27 - rA)) * S_H + q * 8;
    }
    int rw[2][4], hoffs[2][4], coffs[2][4], xoffs[2][4];
#pragma unroll
    for (int u = 0; u < 2; ++u)
#pragma unroll
        for (int i = 0; i < 4; ++i) {
            int mrow = (wm + 2 * u) * 16 + q * 4 + i;   // C-row = q*4+i
            int r = mrow >> 1; if (r > GRIDN - 1) r = GRIDN - 1;
            int b = mrow & 1;
            rw[u][i]    = r;
            hoffs[u][i] = (b * NSLOT + (27 - r)) * S_H + nb;
            coffs[u][i] = (b * NSLOT + (27 - r)) * S_C + nb;
            int rr = (d & 2) ? (GRIDN - 1 - r) : r;     // dir row-flip
            xoffs[u][i] = ((tile * BT + b) * GRIDN + rr) * GRIDN;
        }

    // c_left lives in a register: the lane that writes c(r,c-1) is the lane
    // that consumes it next step. Zero until the row activates.
    float creg[2][4] = {{0.f,0.f,0.f,0.f},{0.f,0.f,0.f,0.f}};

    __syncthreads();   // zero-init complete

    // ---- one or two tasks of one anti-diagonal step. ulo/ucnt are literals
    // at every callsite -> loops unroll, array indices const-fold.
    auto tasks = [&](int t, const f16* FhR, f16* FhW,
                     const float* FcR, float* FcW,
                     int ulo, int ucnt) __attribute__((always_inline)) {
        f16x8 a[2][4];
        float xv[2][4], pcu[2][4];
        bool  act[2][4];
#pragma unroll
        for (int k = 0; k < ucnt; ++k) {
            const int u = ulo + k;
            const f16* ab = FhR + aoffs[u];
            a[u][0] = *(const f16x8*)(ab);               // h_left k 0..31
            a[u][1] = *(const f16x8*)(ab + 32);          // h_left k 32..63
            a[u][2] = *(const f16x8*)(ab + S_H);         // h_up   k 0..31
            a[u][3] = *(const f16x8*)(ab + S_H + 32);    // h_up   k 32..63
        }
#pragma unroll
        for (int k = 0; k < ucnt; ++k) {
            const int u = ulo + k;
#pragma unroll
            for (int i = 0; i < 4; ++i) {
                int r = rw[u][i];
                int c = t - r;
                act[u][i] = ((unsigned)c <= 27u);        // r<=t && r>=t-27
                c = c < 0 ? 0 : (c > 27 ? 27 : c);       // clamp for garbage rows
                int cc = (d & 1) ? (GRIDN - 1 - c) : c;  // dir col-flip
                xv[u][i]  = x[xoffs[u][i] + cc];         // global, L1-resident
                pcu[u][i] = FcR[coffs[u][i] + S_C];      // c_up (row above)
            }
        }
        f32x4 acc[2][5];
#pragma unroll
        for (int k = 0; k < ucnt; ++k) {
            const int u = ulo + k;
#pragma unroll
            for (int g = 0; g < 5; ++g) {
                f32x4 ci;
#pragma unroll
                for (int i = 0; i < 4; ++i) ci[i] = sB[g] + sWx[g] * xv[u][i];
                acc[u][g] = ci;                          // C-init = sc*(x*Wx+b)
            }
        }
        // 20 MFMAs/task; ks outer -> 5*ucnt independent 4-deep chains
#pragma unroll
        for (int ks = 0; ks < 4; ++ks)
#pragma unroll
            for (int k = 0; k < ucnt; ++k) {
                const int u = ulo + k;
#pragma unroll
                for (int g = 0; g < 5; ++g)
                    acc[u][g] = __builtin_amdgcn_mfma_f32_16x16x32_f16(
                        a[u][ks], bf[g][ks], acc[u][g], 0, 0, 0);
            }
        // ---- gates + state, trans-merged (same math as R12):
        //   sig(i)*tanh(g)        = (tb-2)*rcp(ta*tb)
        //   sig(f1)*cl+sig(f2)*cu = (cl*tq+cu*tp)*rcp(tp*tq)
        //   sig(o)*tanh(cn)       = (te-2)*rcp(td*te), cn clamped to 22 for
        //   te only (tanh(22)==1.0f exactly; prevents inf*0=NaN).
#pragma unroll
        for (int k = 0; k < ucnt; ++k) {
            const int u = ulo + k;
#pragma unroll
            for (int i = 0; i < 4; ++i) {
                float ta = 1.0f + ex2(acc[u][0][i]);
                float tp = 1.0f + ex2(acc[u][1][i]);
                float tq = 1.0f + ex2(acc[u][2][i]);
                float td = 1.0f + ex2(acc[u][3][i]);
                float tb = 1.0f + ex2(acc[u][4][i]);
                float cn = (tb - 2.0f) * rcpf(ta * tb)
                         + (creg[u][i] * tq + pcu[u][i] * tp) * rcpf(tp * tq);
                float cnc = fminf(cn, 22.0f);
                float te = 1.0f + ex2(LOG2E2 * cnc);
                float hn = (te - 2.0f) * rcpf(td * te);
                if (act[u][i]) {                         // masked store+update
                    creg[u][i] = cn;
                    FcW[coffs[u][i]] = cn;
                    FhW[hoffs[u][i]] = (f16)hn;
                }
            }
        }
    };

    // one anti-diagonal; br is a literal at every callsite -> const-folds.
    // Tile T (rows 8T..8T+7) is active iff 8T <= t <= 8T+34.
    auto step = [&](int t, int br) __attribute__((always_inline)) {
        const int bw = br ^ 1;
        const f16*   FhR = &Fh[br][0][0];
        f16*         FhW = &Fh[bw][0][0];
        const float* FcR = &Fc[br][0][0];
        float*       FcW = &Fc[bw][0][0];
        const int T0 = wm, T1 = wm + 2;
        bool a0v = (8 * T0 <= t) && (t <= 8 * T0 + 34);
        bool a1v = (8 * T1 <= t) && (t <= 8 * T1 + 34);
        if (a0v && a1v)      tasks(t, FhR, FhW, FcR, FcW, 0, 2);
        else if (a0v)        tasks(t, FhR, FhW, FcR, FcW, 0, 1);
        else if (a1v)        tasks(t, FhR, FhW, FcR, FcW, 1, 1);
        __syncthreads();
    };

    for (int tb = 0; tb < 27; ++tb) { step(2 * tb, 0); step(2 * tb + 1, 1); }
    step(54, 0);

    // final h(27,27): t=54 wrote buf 1, slot 0
    if (tid < BT * HID) {
        int bl = tid >> 6, h = tid & 63;
        Hout[(d * BATCH + tile * BT + bl) * HID + h] = (float)Fh[1][bl][h];
    }
}

// FC head, one WG per batch row. z1 (512 cols) by 256 threads x 2 cols with
// coalesced W1 reads; z2 via 16-slice x 16-col partials + LDS reduce;
// softmax over 10 by one thread.
__global__ __launch_bounds__(256)
void fc_kernel(const float* __restrict__ Hin,  // [4][B][64]
               const float* __restrict__ W1, const float* __restrict__ b1,
               const float* __restrict__ W2, const float* __restrict__ b2,
               float* __restrict__ out)        // [B][10]
{
    const int b   = blockIdx.x;
    const int tid = threadIdx.x;
    __shared__ float hrow[NDIR * HID];
    __shared__ float z1[FC_HD];
    __shared__ float ps[16][16];
    __shared__ float z2[16];

    hrow[tid] = Hin[(tid >> 6) * (BATCH * HID) + b * HID + (tid & 63)];
    __syncthreads();

    // ---- z1 = relu(hrow @ W1 + b1): each thread cols {tid, tid+256}
    {
        float s0 = b1[tid], s1 = b1[tid + 256];
#pragma unroll 8
        for (int f = 0; f < NDIR * HID; ++f) {
            float h = hrow[f];
            s0 += h * W1[f * FC_HD + tid];
            s1 += h * W1[f * FC_HD + tid + 256];
        }
        z1[tid]       = fmaxf(s0, 0.0f);
        z1[tid + 256] = fmaxf(s1, 0.0f);
    }
    __syncthreads();

    // ---- z2 partials: j = tid&15 (10 used), slice = tid>>4 covers 32 k each
    {
        int j = tid & 15, sl = tid >> 4;
        float s = 0.0f;
        if (j < OUT_N) {
#pragma unroll
            for (int i = 0; i < 32; ++i) {
                int kk = sl * 32 + i;
                s += z1[kk] * W2[kk * OUT_N + j];
            }
        }
        ps[sl][j] = s;
    }
    __syncthreads();

    if (tid < OUT_N) {
        float s = b2[tid];
#pragma unroll
        for (int sl = 0; sl < 16; ++sl) s += ps[sl][tid];
        z2[tid] = s;
    }
    __syncthreads();

    if (tid == 0) {
        float m = z2[0];
        for (int j = 1; j < OUT_N; ++j) m = fmaxf(m, z2[j]);
        float sum = 0.0f, e[OUT_N];
        for (int j = 0; j < OUT_N; ++j) { e[j] = __expf(z2[j] - m); sum += e[j]; }
        float inv = 1.0f / sum;
        for (int j = 0; j < OUT_N; ++j) out[b * OUT_N + j] = e[j] * inv;
    }
}

extern "C" void kernel_launch(void* const* d_in, const int* in_sizes, int n_in,
                              void* d_out, int out_size, void* d_ws, size_t ws_size,
                              hipStream_t stream) {
    const float* x  = (const float*)d_in[0];
    const float* Wx = (const float*)d_in[1];
    const float* U  = (const float*)d_in[2];
    const float* bs = (const float*)d_in[3];
    const float* W1 = (const float*)d_in[4];
    const float* b1 = (const float*)d_in[5];
    const float* W2 = (const float*)d_in[6];
    const float* b2 = (const float*)d_in[7];
    float* out = (float*)d_out;
    float* Hws = (float*)d_ws;   // [4][128][64] fp32 = 128 KiB

    mdlstm_kernel<<<NDIR * (BATCH / BT), NTHR, 0, stream>>>(x, Wx, U, bs, Hws);
    fc_kernel<<<BATCH, 256, 0, stream>>>(Hws, W1, b1, W2, b2, out);
}